// Round 1
// baseline (927.407 us; speedup 1.0000x reference)
//
#include <hip/hip_runtime.h>
#include <cstdint>
#include <cstddef>

#define DIM 2048
#define NHEADS 16
#define HD 128
#define HIDDEN 8192
#define BSZ 2
#define SEQ 2048
#define MTOT (BSZ*SEQ)   // 4096 rows total

typedef __bf16 bf16_t;
typedef __bf16 bf16x8 __attribute__((ext_vector_type(8)));
typedef __bf16 bf16x4 __attribute__((ext_vector_type(4)));
typedef float  f32x4  __attribute__((ext_vector_type(4)));

// async global->LDS, 16B per lane. LDS dest must be the WAVE-UNIFORM base;
// HW adds lane*16. Global src is per-lane.
__device__ __forceinline__ void gload16(const void* g, void* lds) {
  __builtin_amdgcn_global_load_lds(
      (const __attribute__((address_space(1))) uint32_t*)g,
      (__attribute__((address_space(3))) uint32_t*)lds, 16, 0, 0);
}

// ---------------------------------------------------------------- cvt fp32->bf16
__global__ void cvt_k(const float* __restrict__ src, bf16_t* __restrict__ dst, int n4) {
  int i = blockIdx.x * blockDim.x + threadIdx.x;
  int stride = gridDim.x * blockDim.x;
  for (; i < n4; i += stride) {
    float4 v = ((const float4*)src)[i];
    bf16x4 o = {(__bf16)v.x, (__bf16)v.y, (__bf16)v.z, (__bf16)v.w};
    ((bf16x4*)dst)[i] = o;
  }
}

// ---------------------------------------------------------------- RMSNorm (fp32 in -> bf16 out)
__global__ __launch_bounds__(256)
void rmsnorm_k(const float* __restrict__ x, const float* __restrict__ wt,
               bf16_t* __restrict__ out) {
  const int row = blockIdx.x;
  const float* xr = x + (size_t)row * DIM;
  const int tid = threadIdx.x;
  float4 a = ((const float4*)xr)[tid];
  float4 b = ((const float4*)xr)[tid + 256];
  float ss = a.x*a.x + a.y*a.y + a.z*a.z + a.w*a.w
           + b.x*b.x + b.y*b.y + b.z*b.z + b.w*b.w;
  #pragma unroll
  for (int d = 32; d >= 1; d >>= 1) ss += __shfl_xor(ss, d, 64);
  __shared__ float red[4];
  if ((tid & 63) == 0) red[tid >> 6] = ss;
  __syncthreads();
  float tot = red[0] + red[1] + red[2] + red[3];
  float rs = rsqrtf(tot * (1.0f / DIM) + 1e-6f);
  float4 wa = ((const float4*)wt)[tid];
  float4 wb = ((const float4*)wt)[tid + 256];
  bf16x4 oa = {(__bf16)(a.x*rs*wa.x), (__bf16)(a.y*rs*wa.y),
               (__bf16)(a.z*rs*wa.z), (__bf16)(a.w*rs*wa.w)};
  bf16x4 ob = {(__bf16)(b.x*rs*wb.x), (__bf16)(b.y*rs*wb.y),
               (__bf16)(b.z*rs*wb.z), (__bf16)(b.w*rs*wb.w)};
  *(bf16x4*)(out + (size_t)row*DIM + tid*4)        = oa;
  *(bf16x4*)(out + (size_t)row*DIM + 1024 + tid*4) = ob;
}

// ---------------------------------------------------------------- NT GEMM (m97 structure)
// C[M,N] = A[M,K] @ B[N,K]^T  (+ residual) (+relu); A,B bf16, acc fp32.
// 128x128 tile, BK=32, 4 waves each 64x64, 16x16x32 MFMA.
template<typename OUT_T, bool RELU, bool HAS_RES>
__global__ __launch_bounds__(256, 3)
void gemm_nt(const bf16_t* __restrict__ A, const bf16_t* __restrict__ B,
             OUT_T* __restrict__ C, const float* __restrict__ res,
             int M, int N, int K) {
  __shared__ bf16_t sA[128 * 32];
  __shared__ bf16_t sB[128 * 32];
  const int tid  = threadIdx.x;
  const int lane = tid & 63;
  const int w    = tid >> 6;
  const int l16  = lane & 15;
  const int g    = lane >> 4;

  // bijective XCD-aware swizzle
  const int nwg = gridDim.x;
  const int bid = blockIdx.x;
  const int qq = nwg >> 3, rr = nwg & 7;
  const int xcd = bid & 7, loc = bid >> 3;
  const int wg = (xcd < rr ? xcd*(qq+1) : rr*(qq+1) + (xcd-rr)*qq) + loc;
  const int nb = N >> 7;
  const int bm = (wg / nb) << 7;
  const int bn = (wg % nb) << 7;

  const int wm = (w >> 1) * 64;
  const int wn = (w & 1) * 64;

  // per-thread staging chunk addresses (element offsets, add k0 per step)
  const int c0 = w*128 + lane;          // chunk ids [0,512): row=c>>2, col8=(c&3)*8
  const int c1 = c0 + 64;
  const size_t aoff0 = (size_t)(bm + (c0 >> 2)) * K + ((c0 & 3) << 3);
  const size_t aoff1 = (size_t)(bm + (c1 >> 2)) * K + ((c1 & 3) << 3);
  const size_t boff0 = (size_t)(bn + (c0 >> 2)) * K + ((c0 & 3) << 3);
  const size_t boff1 = (size_t)(bn + (c1 >> 2)) * K + ((c1 & 3) << 3);
  char* ldsA0 = (char*)sA + (w*128 +  0) * 16;
  char* ldsA1 = (char*)sA + (w*128 + 64) * 16;
  char* ldsB0 = (char*)sB + (w*128 +  0) * 16;
  char* ldsB1 = (char*)sB + (w*128 + 64) * 16;

  f32x4 acc[4][4] = {};

  for (int k0 = 0; k0 < K; k0 += 32) {
    gload16(A + aoff0 + k0, ldsA0);
    gload16(A + aoff1 + k0, ldsA1);
    gload16(B + boff0 + k0, ldsB0);
    gload16(B + boff1 + k0, ldsB1);
    __syncthreads();   // drains vmcnt(0) then barrier

    bf16x8 af[4], bfr[4];
    #pragma unroll
    for (int mt = 0; mt < 4; ++mt)
      af[mt] = *(const bf16x8*)(sA + (wm + mt*16 + l16)*32 + g*8);
    #pragma unroll
    for (int nt = 0; nt < 4; ++nt)
      bfr[nt] = *(const bf16x8*)(sB + (wn + nt*16 + l16)*32 + g*8);
    #pragma unroll
    for (int mt = 0; mt < 4; ++mt)
      #pragma unroll
      for (int nt = 0; nt < 4; ++nt)
        acc[mt][nt] = __builtin_amdgcn_mfma_f32_16x16x32_bf16(af[mt], bfr[nt], acc[mt][nt], 0, 0, 0);
    __syncthreads();
  }

  // epilogue: C row = (lane>>4)*4 + r within 16x16 tile, col = lane&15
  #pragma unroll
  for (int mt = 0; mt < 4; ++mt) {
    #pragma unroll
    for (int r = 0; r < 4; ++r) {
      const int row = bm + wm + mt*16 + g*4 + r;
      #pragma unroll
      for (int nt = 0; nt < 4; ++nt) {
        const int col = bn + wn + nt*16 + l16;
        float v = acc[mt][nt][r];
        if (HAS_RES) v += res[(size_t)row * N + col];
        if (RELU)    v = fmaxf(v, 0.0f);
        C[(size_t)row * N + col] = (OUT_T)v;
      }
    }
  }
}

// ---------------------------------------------------------------- causal flash attention
// grid (S/128, NHEADS, BSZ); 4 waves; wave w owns 32 q-rows; KV-tile 32.
__global__ __launch_bounds__(256, 2)
void attn_k(const bf16_t* __restrict__ Q, const bf16_t* __restrict__ Kk,
            const bf16_t* __restrict__ V, bf16_t* __restrict__ O) {
  __shared__ bf16_t sK[32 * 128];    // [kv][d]
  __shared__ bf16_t sVT[128 * 32];   // [d][kv]
  __shared__ bf16_t sP[4][32 * 32];  // per-wave P tile [m][kv]
  const int tid = threadIdx.x, lane = tid & 63, w = tid >> 6;
  const int l16 = lane & 15, g = lane >> 4;
  const int b = blockIdx.z, h = blockIdx.y, qt = blockIdx.x;
  const int ch = h * HD;
  const size_t gb = (size_t)b * SEQ * DIM;
  const int qbase = qt*128 + w*32;

  // hoist Q fragments: qf[mt][kb], m = mt*16+l16, k = kb*32 + g*8
  bf16x8 qf[2][4];
  #pragma unroll
  for (int mt = 0; mt < 2; ++mt)
    #pragma unroll
    for (int kb = 0; kb < 4; ++kb)
      qf[mt][kb] = *(const bf16x8*)(Q + gb + (size_t)(qbase + mt*16 + l16)*DIM + ch + kb*32 + g*8);

  f32x4 o[2][8] = {};
  float m_r[2][4], l_r[2][4];
  #pragma unroll
  for (int mt = 0; mt < 2; ++mt)
    #pragma unroll
    for (int r = 0; r < 4; ++r) { m_r[mt][r] = -1e9f; l_r[mt][r] = 0.0f; }

  const float rs = 0.08838834764831845f; // 1/sqrt(128)
  const int kend = qt*128 + 128;

  for (int kv0 = 0; kv0 < kend; kv0 += 32) {
    // ---- stage K tile (global_load_lds): 512 x 16B chunks
    #pragma unroll
    for (int i = 0; i < 2; ++i) {
      int c = w*128 + i*64 + lane;          // row = c>>4 (16 chunks/row of 128 cols)
      gload16(Kk + gb + (size_t)(kv0 + (c >> 4))*DIM + ch + ((c & 15) << 3),
              (char*)sK + (w*128 + i*64) * 16);
    }
    // ---- stage V transposed (register path, scalar LDS writes)
    {
      const int kv = tid >> 3, d0 = (tid & 7) << 4;
      const bf16_t* vp = V + gb + (size_t)(kv0 + kv)*DIM + ch + d0;
      bf16x8 v0 = *(const bf16x8*)(vp);
      bf16x8 v1 = *(const bf16x8*)(vp + 8);
      #pragma unroll
      for (int j = 0; j < 8; ++j) sVT[(d0 + j)*32 + kv]     = v0[j];
      #pragma unroll
      for (int j = 0; j < 8; ++j) sVT[(d0 + 8 + j)*32 + kv] = v1[j];
    }
    __syncthreads();

    const bool active = (kv0 < qbase + 32);   // wave-uniform causal skip
    if (active) {
      // ---- S = Q K^T
      f32x4 s[2][2] = {};
      bf16x8 kf[2][4];
      #pragma unroll
      for (int nt = 0; nt < 2; ++nt)
        #pragma unroll
        for (int kb = 0; kb < 4; ++kb)
          kf[nt][kb] = *(const bf16x8*)(sK + (nt*16 + l16)*128 + kb*32 + g*8);
      #pragma unroll
      for (int mt = 0; mt < 2; ++mt)
        #pragma unroll
        for (int nt = 0; nt < 2; ++nt)
          #pragma unroll
          for (int kb = 0; kb < 4; ++kb)
            s[mt][nt] = __builtin_amdgcn_mfma_f32_16x16x32_bf16(qf[mt][kb], kf[nt][kb], s[mt][nt], 0, 0, 0);

      const bool needmask = (kv0 + 31 > qbase);
      // ---- online softmax per row
      #pragma unroll
      for (int mt = 0; mt < 2; ++mt) {
        #pragma unroll
        for (int r = 0; r < 4; ++r) {
          const int qpos = qbase + mt*16 + g*4 + r;
          float s0 = s[mt][0][r] * rs;
          float s1 = s[mt][1][r] * rs;
          if (needmask) {
            if (kv0 + l16 > qpos)      s0 = -1e9f;
            if (kv0 + 16 + l16 > qpos) s1 = -1e9f;
          }
          float mx = fmaxf(s0, s1);
          #pragma unroll
          for (int d = 8; d >= 1; d >>= 1) mx = fmaxf(mx, __shfl_xor(mx, d, 16));
          const float mo = m_r[mt][r];
          const float mn = fmaxf(mo, mx);
          const float sc = __expf(mo - mn);
          const float p0 = __expf(s0 - mn);
          const float p1 = __expf(s1 - mn);
          float rsum = p0 + p1;
          #pragma unroll
          for (int d = 8; d >= 1; d >>= 1) rsum += __shfl_xor(rsum, d, 16);
          l_r[mt][r] = l_r[mt][r] * sc + rsum;
          m_r[mt][r] = mn;
          #pragma unroll
          for (int dt = 0; dt < 8; ++dt) o[mt][dt][r] *= sc;
          sP[w][(mt*16 + g*4 + r)*32 + l16]      = (bf16_t)p0;
          sP[w][(mt*16 + g*4 + r)*32 + 16 + l16] = (bf16_t)p1;
        }
      }
    }
    __syncthreads();   // sP lgkm drain (and keep waves in lockstep)

    if (active) {
      // ---- O += P V
      bf16x8 pa[2];
      #pragma unroll
      for (int mt = 0; mt < 2; ++mt)
        pa[mt] = *(const bf16x8*)(&sP[w][(mt*16 + l16)*32 + g*8]);
      #pragma unroll
      for (int dt = 0; dt < 8; ++dt) {
        bf16x8 vf = *(const bf16x8*)(sVT + (dt*16 + l16)*32 + g*8);
        #pragma unroll
        for (int mt = 0; mt < 2; ++mt)
          o[mt][dt] = __builtin_amdgcn_mfma_f32_16x16x32_bf16(pa[mt], vf, o[mt][dt], 0, 0, 0);
      }
    }
    __syncthreads();   // protect sK/sVT before next staging
  }

  // ---- finalize: O /= l, store
  #pragma unroll
  for (int mt = 0; mt < 2; ++mt) {
    #pragma unroll
    for (int r = 0; r < 4; ++r) {
      const float inv = 1.0f / l_r[mt][r];
      const int row = qbase + mt*16 + g*4 + r;
      #pragma unroll
      for (int dt = 0; dt < 8; ++dt)
        O[gb + (size_t)row*DIM + ch + dt*16 + l16] = (bf16_t)(o[mt][dt][r] * inv);
    }
  }
}

// ---------------------------------------------------------------- launcher
extern "C" void kernel_launch(void* const* d_in, const int* in_sizes, int n_in,
                              void* d_out, int out_size, void* d_ws, size_t ws_size,
                              hipStream_t stream) {
  const float* x   = (const float*)d_in[0];
  // d_in[1] = mask (causal; implemented analytically)
  const float* wq  = (const float*)d_in[2];
  const float* wk  = (const float*)d_in[3];
  const float* wv  = (const float*)d_in[4];
  const float* wo  = (const float*)d_in[5];
  const float* w1  = (const float*)d_in[6];
  const float* w2  = (const float*)d_in[7];
  const float* anw = (const float*)d_in[8];
  const float* fnw = (const float*)d_in[9];
  float* out = (float*)d_out;

  char* p = (char*)d_ws;
  bf16_t* wqb = (bf16_t*)p; p += (size_t)DIM*DIM*2;
  bf16_t* wkb = (bf16_t*)p; p += (size_t)DIM*DIM*2;
  bf16_t* wvb = (bf16_t*)p; p += (size_t)DIM*DIM*2;
  bf16_t* wob = (bf16_t*)p; p += (size_t)DIM*DIM*2;
  bf16_t* w1b = (bf16_t*)p; p += (size_t)DIM*HIDDEN*2;
  bf16_t* w2b = (bf16_t*)p; p += (size_t)DIM*HIDDEN*2;
  bf16_t* xn  = (bf16_t*)p; p += (size_t)MTOT*DIM*2;       // reused as hn
  float*  hb  = (float*)p;  p += (size_t)MTOT*DIM*4;
  bf16_t* big = (bf16_t*)p; p += (size_t)MTOT*HIDDEN*2;    // {q,k,v,attn} then f1
  bf16_t* qb = big;
  bf16_t* kb = big + (size_t)MTOT*DIM;
  bf16_t* vb = big + 2*(size_t)MTOT*DIM;
  bf16_t* ab = big + 3*(size_t)MTOT*DIM;
  bf16_t* f1 = big;

  auto cvt = [&](const float* s, bf16_t* d, size_t n) {
    int n4 = (int)(n / 4);
    int blocks = (n4 + 255) / 256; if (blocks > 4096) blocks = 4096;
    cvt_k<<<blocks, 256, 0, stream>>>(s, d, n4);
  };
  cvt(wq, wqb, (size_t)DIM*DIM);
  cvt(wk, wkb, (size_t)DIM*DIM);
  cvt(wv, wvb, (size_t)DIM*DIM);
  cvt(wo, wob, (size_t)DIM*DIM);
  cvt(w1, w1b, (size_t)DIM*HIDDEN);
  cvt(w2, w2b, (size_t)DIM*HIDDEN);

  rmsnorm_k<<<MTOT, 256, 0, stream>>>(x, anw, xn);

  gemm_nt<bf16_t, false, false><<<512, 256, 0, stream>>>(xn, wqb, qb, nullptr, MTOT, DIM, DIM);
  gemm_nt<bf16_t, false, false><<<512, 256, 0, stream>>>(xn, wkb, kb, nullptr, MTOT, DIM, DIM);
  gemm_nt<bf16_t, false, false><<<512, 256, 0, stream>>>(xn, wvb, vb, nullptr, MTOT, DIM, DIM);

  attn_k<<<dim3(SEQ/128, NHEADS, BSZ), 256, 0, stream>>>(qb, kb, vb, ab);

  gemm_nt<float, false, true><<<512, 256, 0, stream>>>(ab, wob, hb, x, MTOT, DIM, DIM);

  rmsnorm_k<<<MTOT, 256, 0, stream>>>(hb, fnw, xn);

  gemm_nt<bf16_t, true, false><<<2048, 256, 0, stream>>>(xn, w1b, f1, nullptr, MTOT, HIDDEN, DIM);

  gemm_nt<float, false, true><<<512, 256, 0, stream>>>(f1, w2b, out, hb, MTOT, DIM, HIDDEN);
}

// Round 3
// 837.546 us; speedup vs baseline: 1.1073x; 1.1073x over previous
//
#include <hip/hip_runtime.h>
#include <cstdint>
#include <cstddef>

#define DIM 2048
#define NHEADS 16
#define HD 128
#define HIDDEN 8192
#define BSZ 2
#define SEQ 2048
#define MTOT (BSZ*SEQ)   // 4096 rows total

typedef __bf16 bf16_t;
typedef __bf16 bf16x8 __attribute__((ext_vector_type(8)));
typedef __bf16 bf16x4 __attribute__((ext_vector_type(4)));
typedef float  f32x4  __attribute__((ext_vector_type(4)));

// async global->LDS, 16B per lane. LDS dest must be the WAVE-UNIFORM base;
// HW adds lane*16. Global src is per-lane.
__device__ __forceinline__ void gload16(const void* g, void* lds) {
  __builtin_amdgcn_global_load_lds(
      (const __attribute__((address_space(1))) uint32_t*)g,
      (__attribute__((address_space(3))) uint32_t*)lds, 16, 0, 0);
}

// ---------------------------------------------------------------- cvt fp32->bf16
__global__ void cvt_k(const float* __restrict__ src, bf16_t* __restrict__ dst, int n4) {
  int i = blockIdx.x * blockDim.x + threadIdx.x;
  int stride = gridDim.x * blockDim.x;
  for (; i < n4; i += stride) {
    float4 v = ((const float4*)src)[i];
    bf16x4 o = {(__bf16)v.x, (__bf16)v.y, (__bf16)v.z, (__bf16)v.w};
    ((bf16x4*)dst)[i] = o;
  }
}

// ---------------------------------------------------------------- RMSNorm (fp32 in -> bf16 out)
__global__ __launch_bounds__(256)
void rmsnorm_k(const float* __restrict__ x, const float* __restrict__ wt,
               bf16_t* __restrict__ out) {
  const int row = blockIdx.x;
  const float* xr = x + (size_t)row * DIM;
  const int tid = threadIdx.x;
  float4 a = ((const float4*)xr)[tid];
  float4 b = ((const float4*)xr)[tid + 256];
  float ss = a.x*a.x + a.y*a.y + a.z*a.z + a.w*a.w
           + b.x*b.x + b.y*b.y + b.z*b.z + b.w*b.w;
  #pragma unroll
  for (int d = 32; d >= 1; d >>= 1) ss += __shfl_xor(ss, d, 64);
  __shared__ float red[4];
  if ((tid & 63) == 0) red[tid >> 6] = ss;
  __syncthreads();
  float tot = red[0] + red[1] + red[2] + red[3];
  float rs = rsqrtf(tot * (1.0f / DIM) + 1e-6f);
  float4 wa = ((const float4*)wt)[tid];
  float4 wb = ((const float4*)wt)[tid + 256];
  bf16x4 oa = {(__bf16)(a.x*rs*wa.x), (__bf16)(a.y*rs*wa.y),
               (__bf16)(a.z*rs*wa.z), (__bf16)(a.w*rs*wa.w)};
  bf16x4 ob = {(__bf16)(b.x*rs*wb.x), (__bf16)(b.y*rs*wb.y),
               (__bf16)(b.z*rs*wb.z), (__bf16)(b.w*rs*wb.w)};
  *(bf16x4*)(out + (size_t)row*DIM + tid*4)        = oa;
  *(bf16x4*)(out + (size_t)row*DIM + 1024 + tid*4) = ob;
}

// ---------------------------------------------------------------- NT GEMM (m97 structure)
// C[M,N] = A[M,K] @ B[N,K]^T. VT_OUT: write C transposed per-head into
// vT[b][h][d][s]  (b=row>>11, s=row&2047, h=col>>7, d=col&127), 8B packed.
template<typename OUT_T, bool RELU, bool HAS_RES, bool VT_OUT>
__global__ __launch_bounds__(256, 3)
void gemm_nt(const bf16_t* __restrict__ A, const bf16_t* __restrict__ B,
             OUT_T* __restrict__ C, const float* __restrict__ res,
             int M, int N, int K) {
  __shared__ bf16_t sA[128 * 32];
  __shared__ bf16_t sB[128 * 32];
  const int tid  = threadIdx.x;
  const int lane = tid & 63;
  const int w    = tid >> 6;
  const int l16  = lane & 15;
  const int g    = lane >> 4;

  const int nwg = gridDim.x;
  const int bid = blockIdx.x;
  const int qq = nwg >> 3, rr = nwg & 7;
  const int xcd = bid & 7, loc = bid >> 3;
  const int wg = (xcd < rr ? xcd*(qq+1) : rr*(qq+1) + (xcd-rr)*qq) + loc;
  const int nb = N >> 7;
  const int bm = (wg / nb) << 7;
  const int bn = (wg % nb) << 7;

  const int wm = (w >> 1) * 64;
  const int wn = (w & 1) * 64;

  const int c0 = w*128 + lane;
  const int c1 = c0 + 64;
  const size_t aoff0 = (size_t)(bm + (c0 >> 2)) * K + ((c0 & 3) << 3);
  const size_t aoff1 = (size_t)(bm + (c1 >> 2)) * K + ((c1 & 3) << 3);
  const size_t boff0 = (size_t)(bn + (c0 >> 2)) * K + ((c0 & 3) << 3);
  const size_t boff1 = (size_t)(bn + (c1 >> 2)) * K + ((c1 & 3) << 3);
  char* ldsA0 = (char*)sA + (w*128 +  0) * 16;
  char* ldsA1 = (char*)sA + (w*128 + 64) * 16;
  char* ldsB0 = (char*)sB + (w*128 +  0) * 16;
  char* ldsB1 = (char*)sB + (w*128 + 64) * 16;

  f32x4 acc[4][4] = {};

  for (int k0 = 0; k0 < K; k0 += 32) {
    gload16(A + aoff0 + k0, ldsA0);
    gload16(A + aoff1 + k0, ldsA1);
    gload16(B + boff0 + k0, ldsB0);
    gload16(B + boff1 + k0, ldsB1);
    __syncthreads();

    bf16x8 af[4], bfr[4];
    #pragma unroll
    for (int mt = 0; mt < 4; ++mt)
      af[mt] = *(const bf16x8*)(sA + (wm + mt*16 + l16)*32 + g*8);
    #pragma unroll
    for (int nt = 0; nt < 4; ++nt)
      bfr[nt] = *(const bf16x8*)(sB + (wn + nt*16 + l16)*32 + g*8);
    #pragma unroll
    for (int mt = 0; mt < 4; ++mt)
      #pragma unroll
      for (int nt = 0; nt < 4; ++nt)
        acc[mt][nt] = __builtin_amdgcn_mfma_f32_16x16x32_bf16(af[mt], bfr[nt], acc[mt][nt], 0, 0, 0);
    __syncthreads();
  }

  if (VT_OUT) {
    #pragma unroll
    for (int mt = 0; mt < 4; ++mt) {
      const int row = bm + wm + mt*16 + g*4;   // rows row..row+3 (same 2048-block)
      #pragma unroll
      for (int nt = 0; nt < 4; ++nt) {
        const int col = bn + wn + nt*16 + l16;
        f32x4 a4 = acc[mt][nt];
        bf16x4 v4 = {(__bf16)a4[0], (__bf16)a4[1], (__bf16)a4[2], (__bf16)a4[3]};
        *(bf16x4*)((bf16_t*)C +
            (((size_t)(row >> 11) * NHEADS + (col >> 7)) * HD + (col & 127)) * SEQ
            + (row & 2047)) = v4;
      }
    }
  } else {
    #pragma unroll
    for (int mt = 0; mt < 4; ++mt) {
      #pragma unroll
      for (int r = 0; r < 4; ++r) {
        const int row = bm + wm + mt*16 + g*4 + r;
        #pragma unroll
        for (int nt = 0; nt < 4; ++nt) {
          const int col = bn + wn + nt*16 + l16;
          float v = acc[mt][nt][r];
          if (HAS_RES) v += res[(size_t)row * N + col];
          if (RELU)    v = fmaxf(v, 0.0f);
          C[(size_t)row * N + col] = (OUT_T)v;
        }
      }
    }
  }
}

// ---------------------------------------------------------------- causal flash attention v3
// grid (S/128, NHEADS, BSZ); 4 waves; wave w owns 32 q-rows; KV-tile 32.
// K swizzled [kv][chunk^(kv&7)]; V pre-transposed GLOBALLY (vT[b][h][d][s]),
// staged linearly with chunk-swizzle p^((d>>2)&3). Double-buffered, ONE
// barrier per KV step. No tr_read, no scalar transpose writes.
__global__ __launch_bounds__(256, 2)
void attn_k(const bf16_t* __restrict__ Q, const bf16_t* __restrict__ Kk,
            const bf16_t* __restrict__ VT, bf16_t* __restrict__ O) {
  __shared__ bf16_t sK[2][32 * 128];
  __shared__ bf16_t sVT[2][128 * 32];
  __shared__ bf16_t sP[4][32 * 32];
  const int tid = threadIdx.x, lane = tid & 63, w = tid >> 6;
  const int l16 = lane & 15, g = lane >> 4;
  const int b = blockIdx.z, h = blockIdx.y, qt = blockIdx.x;
  const int ch = h * HD;
  const size_t gb = (size_t)b * SEQ * DIM;
  const int qbase = qt*128 + w*32;
  const bf16_t* VTh = VT + ((size_t)b * NHEADS + h) * ((size_t)HD * SEQ);

  // hoist Q fragments: qf[mt][kb], m = mt*16+l16, k = kb*32 + g*8
  bf16x8 qf[2][4];
  #pragma unroll
  for (int mt = 0; mt < 2; ++mt)
    #pragma unroll
    for (int kb = 0; kb < 4; ++kb)
      qf[mt][kb] = *(const bf16x8*)(Q + gb + (size_t)(qbase + mt*16 + l16)*DIM + ch + kb*32 + g*8);

  f32x4 o[2][8] = {};
  float m_r[2][4], l_r[2][4];
  #pragma unroll
  for (int mt = 0; mt < 2; ++mt)
    #pragma unroll
    for (int r = 0; r < 4; ++r) { m_r[mt][r] = -1e9f; l_r[mt][r] = 0.0f; }

  const float rs = 0.08838834764831845f; // 1/sqrt(128)
  const int nsteps = (qt*128 + 128) >> 5;   // >= 4

  // ---- staging (pre-swizzled global sources, linear LDS dest)
  auto stageK = [&](int buf, int kv0) {
    #pragma unroll
    for (int i = 0; i < 2; ++i) {
      const int c = (w*2 + i)*64 + lane;
      const int kv = c >> 4, pos = c & 15;
      const int qsrc = pos ^ (kv & 7);        // chunk swizzle (involution)
      gload16(Kk + gb + (size_t)(kv0 + kv)*DIM + ch + (qsrc << 3),
              (char*)sK[buf] + (size_t)(w*2 + i)*1024);
    }
  };
  auto stageVT = [&](int buf, int kv0) {
    #pragma unroll
    for (int i = 0; i < 2; ++i) {
      const int c = (w*2 + i)*64 + lane;
      const int d = c >> 2, p = c & 3;
      const int q = p ^ ((d >> 2) & 3);       // chunk swizzle (involution)
      gload16(VTh + (size_t)d * SEQ + kv0 + (q << 3),
              (char*)sVT[buf] + (size_t)(w*2 + i)*1024);
    }
  };

  stageK(0, 0);  stageVT(0, 0);
  stageK(1, 32); stageVT(1, 32);
  __syncthreads();

  int cur = 0;
  for (int t = 0; t < nsteps; ++t) {
    const int kv0 = t << 5;
    const bool active = (kv0 < qbase + 32);   // wave-uniform causal skip
    if (active) {
      // ---- S = Q K^T (swizzled K reads, ~2-way max conflicts)
      f32x4 s[2][2] = {};
      const char* kb_ = (const char*)sK[cur];
      #pragma unroll
      for (int nt = 0; nt < 2; ++nt) {
        const int row = nt*16 + l16;
        #pragma unroll
        for (int kbi = 0; kbi < 4; ++kbi) {
          const int pos = (kbi*4 + g) ^ (l16 & 7);
          bf16x8 kf = *(const bf16x8*)(kb_ + row*256 + (pos << 4));
          #pragma unroll
          for (int mt = 0; mt < 2; ++mt)
            s[mt][nt] = __builtin_amdgcn_mfma_f32_16x16x32_bf16(qf[mt][kbi], kf, s[mt][nt], 0, 0, 0);
        }
      }

      const bool needmask = (kv0 + 31 > qbase);
      char* pb = (char*)sP[w];
      // ---- online softmax per row, write P swizzled
      #pragma unroll
      for (int mt = 0; mt < 2; ++mt) {
        #pragma unroll
        for (int r = 0; r < 4; ++r) {
          const int qpos = qbase + mt*16 + g*4 + r;
          float s0 = s[mt][0][r] * rs;
          float s1 = s[mt][1][r] * rs;
          if (needmask) {
            if (kv0 + l16 > qpos)      s0 = -1e9f;
            if (kv0 + 16 + l16 > qpos) s1 = -1e9f;
          }
          float mx = fmaxf(s0, s1);
          #pragma unroll
          for (int d = 8; d >= 1; d >>= 1) mx = fmaxf(mx, __shfl_xor(mx, d, 16));
          const float mo = m_r[mt][r];
          const float mn = fmaxf(mo, mx);
          const float sc = __expf(mo - mn);
          const float p0 = __expf(s0 - mn);
          const float p1 = __expf(s1 - mn);
          float rsum = p0 + p1;
          #pragma unroll
          for (int d = 8; d >= 1; d >>= 1) rsum += __shfl_xor(rsum, d, 16);
          l_r[mt][r] = l_r[mt][r] * sc + rsum;
          m_r[mt][r] = mn;
          #pragma unroll
          for (int dt = 0; dt < 8; ++dt) o[mt][dt][r] *= sc;
          const int prow = mt*16 + g*4 + r;
          // byte (row*64 + col*2) ^ (((row>>2)&3)<<5); (prow>>2)&3 == g here
          *(bf16_t*)(pb + ((prow*64 +      l16*2) ^ (g << 5))) = (bf16_t)p0;
          *(bf16_t*)(pb + ((prow*64 + 32 + l16*2) ^ (g << 5))) = (bf16_t)p1;
        }
      }

      // ---- read P fragments back (same-wave DS ordering is in-order)
      bf16x8 pa[2];
      #pragma unroll
      for (int mt = 0; mt < 2; ++mt) {
        const int row2 = mt*16 + l16;
        pa[mt] = *(const bf16x8*)((const char*)sP[w] +
                  ((row2*64 + g*16) ^ (((l16 >> 2) & 3) << 5)));
      }

      // ---- O += P V  (contiguous ds_read_b128 from swizzled sVT)
      const bf16_t* vb_ = sVT[cur];
      #pragma unroll
      for (int dt = 0; dt < 8; ++dt) {
        const int d = dt*16 + l16;
        bf16x8 vf = *(const bf16x8*)(vb_ + d*32 + ((g ^ ((d >> 2) & 3)) << 3));
        #pragma unroll
        for (int mt = 0; mt < 2; ++mt)
          o[mt][dt] = __builtin_amdgcn_mfma_f32_16x16x32_bf16(pa[mt], vf, o[mt][dt], 0, 0, 0);
      }
    }
    __syncthreads();   // all waves done reading buf[cur]; own stages drained
    const int knext = (t + 2 < nsteps ? t + 2 : nsteps - 1) << 5;
    stageK(cur, knext);
    stageVT(cur, knext);
    cur ^= 1;
  }

  // ---- finalize: O /= l, store
  #pragma unroll
  for (int mt = 0; mt < 2; ++mt) {
    #pragma unroll
    for (int r = 0; r < 4; ++r) {
      const float inv = 1.0f / l_r[mt][r];
      const int row = qbase + mt*16 + g*4 + r;
      #pragma unroll
      for (int dt = 0; dt < 8; ++dt)
        O[gb + (size_t)row*DIM + ch + dt*16 + l16] = (bf16_t)(o[mt][dt][r] * inv);
    }
  }
}

// ---------------------------------------------------------------- launcher
extern "C" void kernel_launch(void* const* d_in, const int* in_sizes, int n_in,
                              void* d_out, int out_size, void* d_ws, size_t ws_size,
                              hipStream_t stream) {
  const float* x   = (const float*)d_in[0];
  const float* wq  = (const float*)d_in[2];
  const float* wk  = (const float*)d_in[3];
  const float* wv  = (const float*)d_in[4];
  const float* wo  = (const float*)d_in[5];
  const float* w1  = (const float*)d_in[6];
  const float* w2  = (const float*)d_in[7];
  const float* anw = (const float*)d_in[8];
  const float* fnw = (const float*)d_in[9];
  float* out = (float*)d_out;

  char* p = (char*)d_ws;
  bf16_t* wqb = (bf16_t*)p; p += (size_t)DIM*DIM*2;
  bf16_t* wkb = (bf16_t*)p; p += (size_t)DIM*DIM*2;
  bf16_t* wvb = (bf16_t*)p; p += (size_t)DIM*DIM*2;
  bf16_t* wob = (bf16_t*)p; p += (size_t)DIM*DIM*2;
  bf16_t* w1b = (bf16_t*)p; p += (size_t)DIM*HIDDEN*2;
  bf16_t* w2b = (bf16_t*)p; p += (size_t)DIM*HIDDEN*2;
  bf16_t* xn  = (bf16_t*)p; p += (size_t)MTOT*DIM*2;
  float*  hb  = (float*)p;  p += (size_t)MTOT*DIM*4;
  bf16_t* big = (bf16_t*)p; p += (size_t)MTOT*HIDDEN*2;
  bf16_t* qb = big;
  bf16_t* kb = big + (size_t)MTOT*DIM;
  bf16_t* vT = big + 2*(size_t)MTOT*DIM;   // [B][H][HD][SEQ]
  bf16_t* ab = big + 3*(size_t)MTOT*DIM;
  bf16_t* f1 = big;

  auto cvt = [&](const float* s, bf16_t* d, size_t n) {
    int n4 = (int)(n / 4);
    int blocks = (n4 + 255) / 256; if (blocks > 4096) blocks = 4096;
    cvt_k<<<blocks, 256, 0, stream>>>(s, d, n4);
  };
  cvt(wq, wqb, (size_t)DIM*DIM);
  cvt(wk, wkb, (size_t)DIM*DIM);
  cvt(wv, wvb, (size_t)DIM*DIM);
  cvt(wo, wob, (size_t)DIM*DIM);
  cvt(w1, w1b, (size_t)DIM*HIDDEN);
  cvt(w2, w2b, (size_t)DIM*HIDDEN);

  rmsnorm_k<<<MTOT, 256, 0, stream>>>(x, anw, xn);

  gemm_nt<bf16_t, false, false, false><<<512, 256, 0, stream>>>(xn, wqb, qb, nullptr, MTOT, DIM, DIM);
  gemm_nt<bf16_t, false, false, false><<<512, 256, 0, stream>>>(xn, wkb, kb, nullptr, MTOT, DIM, DIM);
  gemm_nt<bf16_t, false, false, true ><<<512, 256, 0, stream>>>(xn, wvb, vT, nullptr, MTOT, DIM, DIM);

  attn_k<<<dim3(SEQ/128, NHEADS, BSZ), 256, 0, stream>>>(qb, kb, vT, ab);

  gemm_nt<float, false, true, false><<<512, 256, 0, stream>>>(ab, wob, hb, x, MTOT, DIM, DIM);

  rmsnorm_k<<<MTOT, 256, 0, stream>>>(hb, fnw, xn);

  gemm_nt<bf16_t, true, false, false><<<2048, 256, 0, stream>>>(xn, w1b, f1, nullptr, MTOT, HIDDEN, DIM);

  gemm_nt<float, false, true, false><<<512, 256, 0, stream>>>(f1, w2b, out, hb, MTOT, DIM, HIDDEN);
}